// Round 1
// baseline (113.452 us; speedup 1.0000x reference)
//
#include <hip/hip_runtime.h>
#include <hip/hip_bf16.h>

typedef __bf16 bf16x8 __attribute__((ext_vector_type(8)));
typedef float f32x4 __attribute__((ext_vector_type(4)));

// One wave computes a 64-row x 128-col tile of q. Block = 4 waves = 256 rows.
// No LDS, no __syncthreads: rows are wave-private, and K=128 cols fit in one
// wave's accumulators so row-normalization is a 16-lane shfl butterfly.
__global__ __launch_bounds__(256, 2)
void cluster_q_mfma(const float* __restrict__ x,
                    const float* __restrict__ c,
                    float* __restrict__ out)
{
    const int l = threadIdx.x & 63;
    const int w = threadIdx.x >> 6;
    const int m = l & 15;          // A-row / B-col within fragment
    const int g = l >> 4;          // k-group (0..3), 8 contiguous k each
    const long rowbase = (long)blockIdx.x * 256 + w * 64;

    f32x4 acc[4][8];
#pragma unroll
    for (int i = 0; i < 4; ++i)
#pragma unroll
        for (int j = 0; j < 8; ++j) acc[i][j] = f32x4{0.f, 0.f, 0.f, 0.f};

    float x2p[4] = {0.f, 0.f, 0.f, 0.f};
    float c2p[8] = {0.f, 0.f, 0.f, 0.f, 0.f, 0.f, 0.f, 0.f};

    const float* xb = x + (rowbase + m) * 512 + g * 8;
    const float* cb = c + m * 512 + g * 8;

#pragma unroll 1
    for (int kk = 0; kk < 16; ++kk) {
        const int kb = kk * 32;
        bf16x8 aF[4], bF[8];
#pragma unroll
        for (int rb = 0; rb < 4; ++rb) {
            const float* p = xb + rb * (16 * 512) + kb;
            f32x4 u0 = *(const f32x4*)p;
            f32x4 u1 = *(const f32x4*)(p + 4);
#pragma unroll
            for (int j = 0; j < 4; ++j) {
                aF[rb][j]     = (__bf16)u0[j];
                aF[rb][4 + j] = (__bf16)u1[j];
                x2p[rb] += u0[j] * u0[j];
                x2p[rb] += u1[j] * u1[j];
            }
        }
#pragma unroll
        for (int nb = 0; nb < 8; ++nb) {
            const float* p = cb + nb * (16 * 512) + kb;
            f32x4 u0 = *(const f32x4*)p;
            f32x4 u1 = *(const f32x4*)(p + 4);
#pragma unroll
            for (int j = 0; j < 4; ++j) {
                bF[nb][j]     = (__bf16)u0[j];
                bF[nb][4 + j] = (__bf16)u1[j];
                c2p[nb] += u0[j] * u0[j];
                c2p[nb] += u1[j] * u1[j];
            }
        }
#pragma unroll
        for (int rb = 0; rb < 4; ++rb)
#pragma unroll
            for (int nb = 0; nb < 8; ++nb)
                acc[rb][nb] = __builtin_amdgcn_mfma_f32_16x16x32_bf16(
                    aF[rb], bF[nb], acc[rb][nb], 0, 0, 0);
    }

    // Complete x2/c2 sums across the 4 k-groups (lanes m, m+16, m+32, m+48).
#pragma unroll
    for (int rb = 0; rb < 4; ++rb) {
        x2p[rb] += __shfl_xor(x2p[rb], 16);
        x2p[rb] += __shfl_xor(x2p[rb], 32);
    }
#pragma unroll
    for (int nb = 0; nb < 8; ++nb) {
        c2p[nb] += __shfl_xor(c2p[nb], 16);
        c2p[nb] += __shfl_xor(c2p[nb], 32);
    }

    // Epilogue. C/D layout: col = m, row(within 16-block) = g*4 + r.
#pragma unroll
    for (int rb = 0; rb < 4; ++rb) {
        float x2r[4], rs[4];
#pragma unroll
        for (int r = 0; r < 4; ++r) {
            x2r[r] = __shfl(x2p[rb], g * 4 + r);  // x2 of the row this lane owns
            rs[r] = 0.f;
        }
#pragma unroll
        for (int nb = 0; nb < 8; ++nb) {
#pragma unroll
            for (int r = 0; r < 4; ++r) {
                float d2 = x2r[r] + c2p[nb] - 2.f * acc[rb][nb][r];
                d2 = fmaxf(d2, 0.f);
                float q = 1.f / (1.f + d2);     // ALPHA=1, exponent (a+1)/2 = 1
                acc[rb][nb][r] = q;
                rs[r] += q;
            }
        }
#pragma unroll
        for (int r = 0; r < 4; ++r) {
            rs[r] += __shfl_xor(rs[r], 1);
            rs[r] += __shfl_xor(rs[r], 2);
            rs[r] += __shfl_xor(rs[r], 4);
            rs[r] += __shfl_xor(rs[r], 8);
            rs[r] = 1.f / rs[r];
        }
        const long orow = rowbase + rb * 16 + g * 4;
#pragma unroll
        for (int nb = 0; nb < 8; ++nb) {
#pragma unroll
            for (int r = 0; r < 4; ++r) {
                out[(orow + r) * 128 + nb * 16 + m] = acc[rb][nb][r] * rs[r];
            }
        }
    }
}

extern "C" void kernel_launch(void* const* d_in, const int* in_sizes, int n_in,
                              void* d_out, int out_size, void* d_ws, size_t ws_size,
                              hipStream_t stream)
{
    const float* x = (const float*)d_in[0];
    const float* c = (const float*)d_in[1];
    float* out = (float*)d_out;
    const int N = in_sizes[0] / 512;          // 131072 rows
    dim3 grid(N / 256), block(256);           // 512 blocks, 4 waves each
    hipLaunchKernelGGL(cluster_q_mfma, grid, block, 0, stream, x, c, out);
}

// Round 2
// 100.464 us; speedup vs baseline: 1.1293x; 1.1293x over previous
//
#include <hip/hip_runtime.h>
#include <hip/hip_bf16.h>

typedef __bf16 bf16x8 __attribute__((ext_vector_type(8)));
typedef float f32x4 __attribute__((ext_vector_type(4)));

// Pre-kernel: convert clusters (128x512 f32) -> bf16 into ws, and c2[128] fp32.
// One wave per cluster row.
__global__ __launch_bounds__(64)
void prep_clusters(const float* __restrict__ c, __bf16* __restrict__ cb,
                   float* __restrict__ c2)
{
    const int row = blockIdx.x;     // 0..127
    const int l = threadIdx.x;      // 0..63
    const float* p = c + row * 512 + l * 8;
    f32x4 u0 = *(const f32x4*)p;
    f32x4 u1 = *(const f32x4*)(p + 4);
    bf16x8 v;
    float s = 0.f;
#pragma unroll
    for (int j = 0; j < 4; ++j) {
        v[j]     = (__bf16)u0[j];
        v[4 + j] = (__bf16)u1[j];
        s += u0[j] * u0[j] + u1[j] * u1[j];
    }
    *(bf16x8*)(cb + row * 512 + l * 8) = v;
#pragma unroll
    for (int off = 32; off >= 1; off >>= 1) s += __shfl_xor(s, off);
    if (l == 0) c2[row] = s;
}

// Main: one wave = 64 rows x 128 cols of q. No LDS, no syncthreads.
// A (x) is streamed from HBM with a 2-deep register double-buffer so loads for
// k-step t+1 are in flight while MFMAs for t run. B (clusters) is pre-converted
// bf16 in ws (L2-resident), loaded just-in-time.
__global__ __launch_bounds__(256, 2)
void cluster_q_mfma(const float* __restrict__ x,
                    const __bf16* __restrict__ cb,
                    const float* __restrict__ c2,
                    float* __restrict__ out)
{
    const int l = threadIdx.x & 63;
    const int w = threadIdx.x >> 6;
    const int m = l & 15;          // fragment row (A) / col (B)
    const int g = l >> 4;          // k-group (0..3), 8 contiguous k each
    const long rowbase = (long)blockIdx.x * 256 + w * 64;

    f32x4 acc[4][8];
#pragma unroll
    for (int i = 0; i < 4; ++i)
#pragma unroll
        for (int j = 0; j < 8; ++j) acc[i][j] = f32x4{0.f, 0.f, 0.f, 0.f};

    float x2p[4] = {0.f, 0.f, 0.f, 0.f};

    const float* xb = x + (rowbase + m) * 512 + g * 8;
    const __bf16* cbp = cb + m * 512 + g * 8;

    f32x4 R0[4][2], R1[4][2];

#define LOAD_R(R, KB)                                                     \
    {                                                                     \
        _Pragma("unroll")                                                 \
        for (int rb = 0; rb < 4; ++rb) {                                  \
            const float* p_ = xb + rb * (16 * 512) + (KB);                \
            R[rb][0] = *(const f32x4*)p_;                                 \
            R[rb][1] = *(const f32x4*)(p_ + 4);                           \
        }                                                                 \
    }

#define COMPUTE(R, KB)                                                    \
    {                                                                     \
        bf16x8 bF[8];                                                     \
        _Pragma("unroll")                                                 \
        for (int nb = 0; nb < 8; ++nb)                                    \
            bF[nb] = *(const bf16x8*)(cbp + nb * (16 * 512) + (KB));      \
        bf16x8 aF[4];                                                     \
        _Pragma("unroll")                                                 \
        for (int rb = 0; rb < 4; ++rb) {                                  \
            _Pragma("unroll")                                             \
            for (int j = 0; j < 4; ++j) {                                 \
                aF[rb][j]     = (__bf16)R[rb][0][j];                      \
                aF[rb][4 + j] = (__bf16)R[rb][1][j];                      \
                x2p[rb] += R[rb][0][j] * R[rb][0][j];                     \
                x2p[rb] += R[rb][1][j] * R[rb][1][j];                     \
            }                                                             \
        }                                                                 \
        _Pragma("unroll")                                                 \
        for (int rb = 0; rb < 4; ++rb) {                                  \
            _Pragma("unroll")                                             \
            for (int nb = 0; nb < 8; ++nb)                                \
                acc[rb][nb] = __builtin_amdgcn_mfma_f32_16x16x32_bf16(    \
                    aF[rb], bF[nb], acc[rb][nb], 0, 0, 0);                \
        }                                                                 \
    }

    LOAD_R(R0, 0);                       // prologue: k-step 0 in flight

#pragma unroll 1
    for (int it = 0; it < 8; ++it) {
        const int kb0 = it * 64;                       // even k-step
        const int kb1 = kb0 + 32;                      // odd k-step
        const int kb2 = (it < 7) ? kb0 + 64 : 0;       // next even (clamped; extra
                                                       // load never consumed)
        LOAD_R(R1, kb1);                 // odd step in flight
        COMPUTE(R0, kb0);                // consume even step
        LOAD_R(R0, kb2);                 // next even step in flight
        COMPUTE(R1, kb1);                // consume odd step
    }
#undef LOAD_R
#undef COMPUTE

    // Complete x2 across the 4 k-groups (lanes m, m+16, m+32, m+48).
#pragma unroll
    for (int rb = 0; rb < 4; ++rb) {
        x2p[rb] += __shfl_xor(x2p[rb], 16);
        x2p[rb] += __shfl_xor(x2p[rb], 32);
    }

    float c2v[8];
#pragma unroll
    for (int nb = 0; nb < 8; ++nb) c2v[nb] = c2[nb * 16 + m];

    // Epilogue. C/D layout: col = m, row(within 16-block) = g*4 + r.
#pragma unroll
    for (int rb = 0; rb < 4; ++rb) {
        float x2r[4], rs[4];
#pragma unroll
        for (int r = 0; r < 4; ++r) {
            x2r[r] = __shfl(x2p[rb], g * 4 + r);
            rs[r] = 0.f;
        }
#pragma unroll
        for (int nb = 0; nb < 8; ++nb) {
#pragma unroll
            for (int r = 0; r < 4; ++r) {
                float d2 = x2r[r] + c2v[nb] - 2.f * acc[rb][nb][r];
                d2 = fmaxf(d2, 0.f);
                float q = 1.f / (1.f + d2);   // ALPHA=1 -> exponent is 1
                acc[rb][nb][r] = q;
                rs[r] += q;
            }
        }
#pragma unroll
        for (int r = 0; r < 4; ++r) {
            rs[r] += __shfl_xor(rs[r], 1);
            rs[r] += __shfl_xor(rs[r], 2);
            rs[r] += __shfl_xor(rs[r], 4);
            rs[r] += __shfl_xor(rs[r], 8);
            rs[r] = 1.f / rs[r];
        }
        const long orow = rowbase + rb * 16 + g * 4;
#pragma unroll
        for (int nb = 0; nb < 8; ++nb) {
#pragma unroll
            for (int r = 0; r < 4; ++r) {
                out[(orow + r) * 128 + nb * 16 + m] = acc[rb][nb][r] * rs[r];
            }
        }
    }
}

extern "C" void kernel_launch(void* const* d_in, const int* in_sizes, int n_in,
                              void* d_out, int out_size, void* d_ws, size_t ws_size,
                              hipStream_t stream)
{
    const float* x = (const float*)d_in[0];
    const float* c = (const float*)d_in[1];
    float* out = (float*)d_out;

    float*  c2ws = (float*)d_ws;                        // 128 floats
    __bf16* cbws = (__bf16*)((char*)d_ws + 1024);       // 128x512 bf16 = 128 KB

    hipLaunchKernelGGL(prep_clusters, dim3(128), dim3(64), 0, stream, c, cbws, c2ws);

    const int N = in_sizes[0] / 512;                    // 131072 rows
    dim3 grid(N / 256), block(256);                     // 512 blocks, 4 waves each
    hipLaunchKernelGGL(cluster_q_mfma, grid, block, 0, stream, x, cbws, c2ws, out);
}

// Round 3
// 87.630 us; speedup vs baseline: 1.2947x; 1.1465x over previous
//
#include <hip/hip_runtime.h>
#include <hip/hip_bf16.h>

typedef __bf16 bf16x8 __attribute__((ext_vector_type(8)));
typedef float f32x4 __attribute__((ext_vector_type(4)));

// Pre-kernel: clusters (128x512 f32) -> bf16 in ws, plus fp32 c2[128].
__global__ __launch_bounds__(64)
void prep_clusters(const float* __restrict__ c, __bf16* __restrict__ cb,
                   float* __restrict__ c2)
{
    const int row = blockIdx.x;     // 0..127
    const int l = threadIdx.x;      // 0..63
    const float* p = c + row * 512 + l * 8;
    f32x4 u0 = *(const f32x4*)p;
    f32x4 u1 = *(const f32x4*)(p + 4);
    bf16x8 v;
    float s = 0.f;
#pragma unroll
    for (int j = 0; j < 4; ++j) {
        v[j]     = (__bf16)u0[j];
        v[4 + j] = (__bf16)u1[j];
        s += u0[j] * u0[j] + u1[j] * u1[j];
    }
    *(bf16x8*)(cb + row * 512 + l * 8) = v;
#pragma unroll
    for (int off = 32; off >= 1; off >>= 1) s += __shfl_xor(s, off);
    if (l == 0) c2[row] = s;
}

__device__ __forceinline__ void gl_lds16(const float* g, float* l)
{
    __builtin_amdgcn_global_load_lds(
        (const __attribute__((address_space(1))) void*)g,
        (__attribute__((address_space(3))) void*)l, 16, 0, 0);
}

// Block = 4 waves = 256 rows x 128 cols. A (x, f32) streamed HBM->LDS via
// global_load_lds, double-buffered, counted vmcnt(8) so the next 32KB tile is
// ALWAYS in flight (never drain to 0 in the loop). B = preconverted bf16 from
// ws (L2). Per-wave 64x128 output -> row-normalize via 16-lane shfl butterfly.
__global__ __launch_bounds__(256, 2)
void cluster_q_mfma(const float* __restrict__ x,
                    const __bf16* __restrict__ cb,
                    const float* __restrict__ c2,
                    float* __restrict__ out)
{
    __shared__ float lds[2][256 * 32];   // 2 x 32 KB k-step tiles (256 rows x 32 k)

    const int tid = threadIdx.x;
    const int l = tid & 63;
    const int w = tid >> 6;
    const int m = l & 15;          // fragment row (A) / col (B)
    const int g = l >> 4;          // k-group (0..3), 8 contiguous k
    const long rowblk = (long)blockIdx.x * 256;

    f32x4 acc[4][8];
#pragma unroll
    for (int i = 0; i < 4; ++i)
#pragma unroll
        for (int j = 0; j < 8; ++j) acc[i][j] = f32x4{0.f, 0.f, 0.f, 0.f};

    float x2p[4] = {0.f, 0.f, 0.f, 0.f};

    // Stage addressing: thread covers (row = i*32 + tid/8, kfloat = (tid%8)*4),
    // LDS float offset = i*1024 + (tid>>3)*32 + (tid&7)*4  (= wave base + lane*16B).
    const float* sbase = x + (rowblk + (tid >> 3)) * 512 + (tid & 7) * 4;
    const int dbase = (tid >> 3) * 32 + (tid & 7) * 4;

    const __bf16* cbp = cb + m * 512 + g * 8;

    // c2 per output column this lane owns (oldest loads; drained by 1st vmcnt).
    float c2v[8];
#pragma unroll
    for (int nb = 0; nb < 8; ++nb) c2v[nb] = c2[nb * 16 + m];

#define STAGE(BUF, K0)                                                    \
    { _Pragma("unroll")                                                   \
      for (int i_ = 0; i_ < 8; ++i_)                                      \
          gl_lds16(sbase + (long)i_ * 16384 + (K0),                       \
                   &lds[BUF][i_ * 1024 + dbase]); }

    STAGE(0, 0);                          // prologue: tile 0 in flight

#pragma unroll 1
    for (int it = 0; it < 16; ++it) {
        const int cur = it & 1;
        const int kb = it * 32;

        // 1) B fragments for this k-step (older than next stage -> covered by vmcnt(8))
        bf16x8 bF[8];
#pragma unroll
        for (int nb = 0; nb < 8; ++nb)
            bF[nb] = *(const bf16x8*)(cbp + nb * (16 * 512) + kb);
        __builtin_amdgcn_sched_barrier(0);

        // 2) stage next tile; 3) counted wait: leave exactly next tile in flight
        if (it < 15) {
            STAGE(cur ^ 1, kb + 32);
            __builtin_amdgcn_sched_barrier(0);
            asm volatile("s_waitcnt vmcnt(8)" ::: "memory");
        } else {
            asm volatile("s_waitcnt vmcnt(0)" ::: "memory");
        }
        __builtin_amdgcn_sched_barrier(0);
        __builtin_amdgcn_s_barrier();     // tile `it` fully in LDS for all waves
        __builtin_amdgcn_sched_barrier(0);

        // 4) compute from LDS: A-frag read f32, convert, x2, 32 MFMA
        bf16x8 aF[4];
#pragma unroll
        for (int rb = 0; rb < 4; ++rb) {
            const float* ap = &lds[cur][(w * 64 + m + rb * 16) * 32 + g * 8];
            f32x4 u0 = *(const f32x4*)ap;
            f32x4 u1 = *(const f32x4*)(ap + 4);
#pragma unroll
            for (int j = 0; j < 4; ++j) {
                aF[rb][j]     = (__bf16)u0[j];
                aF[rb][4 + j] = (__bf16)u1[j];
                x2p[rb] += u0[j] * u0[j];
                x2p[rb] += u1[j] * u1[j];
            }
        }
#pragma unroll
        for (int rb = 0; rb < 4; ++rb)
#pragma unroll
            for (int nb = 0; nb < 8; ++nb)
                acc[rb][nb] = __builtin_amdgcn_mfma_f32_16x16x32_bf16(
                    aF[rb], bF[nb], acc[rb][nb], 0, 0, 0);

        // 5) buffer release: LDS reads done before anyone overwrites this buffer
        asm volatile("s_waitcnt lgkmcnt(0)" ::: "memory");
        __builtin_amdgcn_sched_barrier(0);
        __builtin_amdgcn_s_barrier();
        __builtin_amdgcn_sched_barrier(0);
    }
#undef STAGE

    // Complete x2 across the 4 k-groups (lanes m, m+16, m+32, m+48).
#pragma unroll
    for (int rb = 0; rb < 4; ++rb) {
        x2p[rb] += __shfl_xor(x2p[rb], 16);
        x2p[rb] += __shfl_xor(x2p[rb], 32);
    }

    // Epilogue. C/D layout: col = m, row(within 16-block) = g*4 + r.
#pragma unroll
    for (int rb = 0; rb < 4; ++rb) {
        float x2r[4], rs[4];
#pragma unroll
        for (int r = 0; r < 4; ++r) {
            x2r[r] = __shfl(x2p[rb], g * 4 + r);
            rs[r] = 0.f;
        }
#pragma unroll
        for (int nb = 0; nb < 8; ++nb) {
#pragma unroll
            for (int r = 0; r < 4; ++r) {
                float d2 = x2r[r] + c2v[nb] - 2.f * acc[rb][nb][r];
                d2 = fmaxf(d2, 0.f);
                float q = 1.f / (1.f + d2);   // ALPHA=1 -> exponent is 1
                acc[rb][nb][r] = q;
                rs[r] += q;
            }
        }
#pragma unroll
        for (int r = 0; r < 4; ++r) {
            rs[r] += __shfl_xor(rs[r], 1);
            rs[r] += __shfl_xor(rs[r], 2);
            rs[r] += __shfl_xor(rs[r], 4);
            rs[r] += __shfl_xor(rs[r], 8);
            rs[r] = 1.f / rs[r];
        }
        const long orow = rowblk + w * 64 + rb * 16 + g * 4;
#pragma unroll
        for (int nb = 0; nb < 8; ++nb) {
#pragma unroll
            for (int r = 0; r < 4; ++r) {
                out[(orow + r) * 128 + nb * 16 + m] = acc[rb][nb][r] * rs[r];
            }
        }
    }
}

extern "C" void kernel_launch(void* const* d_in, const int* in_sizes, int n_in,
                              void* d_out, int out_size, void* d_ws, size_t ws_size,
                              hipStream_t stream)
{
    const float* x = (const float*)d_in[0];
    const float* c = (const float*)d_in[1];
    float* out = (float*)d_out;

    float*  c2ws = (float*)d_ws;                        // 128 floats
    __bf16* cbws = (__bf16*)((char*)d_ws + 1024);       // 128x512 bf16 = 128 KB

    hipLaunchKernelGGL(prep_clusters, dim3(128), dim3(64), 0, stream, c, cbws, c2ws);

    const int N = in_sizes[0] / 512;                    // 131072 rows
    dim3 grid(N / 256), block(256);                     // 512 blocks = 2/CU
    hipLaunchKernelGGL(cluster_q_mfma, grid, block, 0, stream, x, cbws, c2ws, out);
}